// Round 5
// baseline (104.998 us; speedup 1.0000x reference)
//
#include <hip/hip_runtime.h>

// Shapes (fixed by the problem)
constexpr int TOK     = 1024 * 2048;  // B*S tokens
constexpr int TPB     = 256;          // threads per block
constexpr int TOK_PB  = 2048;         // tokens per block
constexpr int P1_IT   = TOK_PB / TPB; // 8 pass-1 iters
constexpr int G       = 8;            // sorted tokens per thread in pass 2
constexpr int NBLK    = TOK / TOK_PB; // 1024 blocks

typedef float f32x4 __attribute__((ext_vector_type(4)));

// ws float layout (written by setup_fused):
// [0,32)      Gf[k=4][j=8]       = embed_w^T @ gate_w
// [32,40)     gb[8]              = embed_b @ gate_w
// [40,1064)   Wf[e=8][k=4][f=32] = embed_w^T @ wi[e]
// [1064,1320) ub[e=8][f=32]      = embed_b @ wi[e]
// [1320,2344) Pf[e=8][f=32][o=4] = wo[e] @ proj_w^T
// [2344,2348) pb[4]
constexpr int WS_FLOATS = 2348;

__global__ void setup_fused(
    const float* __restrict__ ew,  // [16][4]
    const float* __restrict__ eb,  // [16]
    const float* __restrict__ gw,  // [16][8]
    const float* __restrict__ wi,  // [8][16][32]
    const float* __restrict__ wo,  // [8][32][16]
    const float* __restrict__ pw,  // [4][16]
    const float* __restrict__ pb,  // [4]
    float* __restrict__ ws)
{
    int idx = blockIdx.x * blockDim.x + threadIdx.x;
    if (idx >= WS_FLOATS) return;
    float v = 0.0f;
    if (idx < 32) {
        int k = idx >> 3, j = idx & 7;
        for (int i = 0; i < 16; ++i) v += ew[i * 4 + k] * gw[i * 8 + j];
    } else if (idx < 40) {
        int j = idx - 32;
        for (int i = 0; i < 16; ++i) v += eb[i] * gw[i * 8 + j];
    } else if (idx < 1064) {
        int r = idx - 40; int e = r >> 7, k = (r >> 5) & 3, f = r & 31;
        for (int i = 0; i < 16; ++i) v += ew[i * 4 + k] * wi[(e * 16 + i) * 32 + f];
    } else if (idx < 1320) {
        int r = idx - 1064; int e = r >> 5, f = r & 31;
        for (int i = 0; i < 16; ++i) v += eb[i] * wi[(e * 16 + i) * 32 + f];
    } else if (idx < 2344) {
        int r = idx - 1320; int e = r >> 7, f = (r >> 2) & 31, o = r & 3;
        for (int i = 0; i < 16; ++i) v += wo[(e * 32 + f) * 16 + i] * pw[o * 16 + i];
    } else {
        v = pb[idx - 2344];
    }
    ws[idx] = v;
}

__device__ __forceinline__ f32x4 splat4(float s) { return (f32x4){s, s, s, s}; }

__global__ __launch_bounds__(256) void moe_main(
    const float* __restrict__ x,   // [T][4]
    const float* __restrict__ ws,  // fused weights
    float* __restrict__ out)       // [T][4]
{
    __shared__ __align__(16) f32x4          s_x[TOK_PB];    // 32 KB: x -> result
    __shared__ float                        s_p[TOK_PB];    // 8 KB: top_p
    __shared__ __align__(16) unsigned short s_sid[TOK_PB];  // 4 KB: sid | e<<11
    __shared__ int s_cnt[8];
    __shared__ int s_base[8];
    __shared__ __align__(16) float sWf[8 * 128];
    __shared__ __align__(16) float sUb[8 * 32];
    __shared__ __align__(16) float sPf[8 * 128];

    const int tid  = threadIdx.x;
    const int lane = tid & 63;
    const unsigned long long lt_mask = (lane == 63) ? 0x7fffffffffffffffull
                                                    : ((1ull << lane) - 1ull);

    if (tid < 8) s_cnt[tid] = 0;
    {   // stage fused weights to LDS (coalesced, once per block)
        int i = tid;
        #pragma unroll
        for (int rep = 0; rep < 4; ++rep, i += 256) {
            sWf[i] = ws[40 + i];
            sPf[i] = ws[1320 + i];
        }
        sUb[tid] = ws[1064 + tid];
    }

    const int gbase = blockIdx.x * TOK_PB;
    const f32x4* __restrict__ x4 = (const f32x4*)x;
    f32x4* __restrict__ o4       = (f32x4*)out;

    // Wave-uniform gate/proj params (scalar broadcast loads from global).
    f32x4 Gr[8];
    #pragma unroll
    for (int q = 0; q < 8; ++q) Gr[q] = ((const f32x4*)ws)[q];
    const f32x4 w_gb0 = ((const f32x4*)ws)[8];
    const f32x4 w_gb1 = ((const f32x4*)ws)[9];
    const f32x4 w_pb  = ((const f32x4*)(ws + 2344))[0];

    constexpr float LOG2E  = 1.4426950408889634f;
    constexpr float GELU_K = 2.3025850929940457f;   // 2*0.7978845608*log2(e)
    constexpr float GELU_B = 0.044715f;
    const f32x4 one4 = splat4(1.0f);

    __syncthreads();

    // ---------------- Pass 1: gate + stash + counting-sort ----------------
    int e_arr[P1_IT], pos_arr[P1_IT];

    #pragma unroll
    for (int it = 0; it < P1_IT; ++it) {
        const int t_loc = it * TPB + tid;
        f32x4 xv = x4[gbase + t_loc];
        s_x[t_loc] = xv;

        f32x4 ga = w_gb0, gb2 = w_gb1;
        #pragma unroll
        for (int k = 0; k < 4; ++k) {
            f32x4 xs = splat4(xv[k]);
            ga  = __builtin_elementwise_fma(xs, Gr[2 * k],     ga);
            gb2 = __builtin_elementwise_fma(xs, Gr[2 * k + 1], gb2);
        }
        float g[8] = {ga[0], ga[1], ga[2], ga[3], gb2[0], gb2[1], gb2[2], gb2[3]};

        float gmax = g[0]; int e = 0;
        #pragma unroll
        for (int j = 1; j < 8; ++j)
            if (g[j] > gmax) { gmax = g[j]; e = j; }
        float ssum = 0.0f;
        #pragma unroll
        for (int j = 0; j < 8; ++j)
            ssum += __builtin_amdgcn_exp2f((g[j] - gmax) * LOG2E);
        s_p[t_loc] = __builtin_amdgcn_rcpf(ssum);

        // wave-aggregated counting: 8 ballots, 8 atomics per wave
        int pos_w = 0, my_cnt = 0;
        #pragma unroll
        for (int j = 0; j < 8; ++j) {
            unsigned long long bj = __ballot(e == j);
            int pc_lt = __popcll(bj & lt_mask);
            int pc    = __popcll(bj);
            if (e == j)    pos_w  = pc_lt;
            if (lane == j) my_cnt = pc;
        }
        int base_w = 0;
        if (lane < 8) base_w = atomicAdd(&s_cnt[lane], my_cnt);
        int base = __shfl(base_w, e, 64);
        e_arr[it]   = e;
        pos_arr[it] = base + pos_w;
    }
    __syncthreads();

    if (tid == 0) {
        int run = 0;
        #pragma unroll
        for (int j = 0; j < 8; ++j) { s_base[j] = run; run += s_cnt[j]; }
    }
    __syncthreads();

    #pragma unroll
    for (int it = 0; it < P1_IT; ++it) {
        const int t_loc = it * TPB + tid;
        const int slot  = s_base[e_arr[it]] + pos_arr[it];
        s_sid[slot] = (unsigned short)(t_loc | (e_arr[it] << 11));
    }
    __syncthreads();

    // ---- Pass 2: G=8 sorted tokens per thread; weights in registers ------
    {
        const int g0 = tid * G;
        // metadata: 8 consecutive u16 = one 16B read
        uint4 meta = *(const uint4*)&s_sid[g0];
        int sid[G], eg[G];
        {
            unsigned mw[4] = {meta.x, meta.y, meta.z, meta.w};
            #pragma unroll
            for (int h = 0; h < 4; ++h) {
                sid[2 * h]     = (int)(mw[h] & 2047u);
                eg[2 * h]      = (int)((mw[h] >> 11) & 7u);
                sid[2 * h + 1] = (int)((mw[h] >> 16) & 2047u);
                eg[2 * h + 1]  = (int)((mw[h] >> 27) & 7u);
            }
        }

        f32x4 xr[G];
        #pragma unroll
        for (int g = 0; g < G; ++g) xr[g] = s_x[sid[g]];
        f32x4 acc[G];
        #pragma unroll
        for (int g = 0; g < G; ++g) acc[g] = splat4(0.0f);

        #pragma unroll 1
        for (int c = 0; c < 8; ++c) {          // 8 f-chunks of 4
            f32x4 wf0, wf1, wf2, wf3, ubv, pf0, pf1, pf2, pf3;
            int cur_e = eg[0];
            auto load_w = [&](int e) {
                const float* wfp = sWf + e * 128 + c * 4;
                wf0 = *(const f32x4*)(wfp + 0);
                wf1 = *(const f32x4*)(wfp + 32);
                wf2 = *(const f32x4*)(wfp + 64);
                wf3 = *(const f32x4*)(wfp + 96);
                ubv = *(const f32x4*)(sUb + e * 32 + c * 4);
                const float* pfp = sPf + e * 128 + c * 16;
                pf0 = *(const f32x4*)(pfp + 0);
                pf1 = *(const f32x4*)(pfp + 4);
                pf2 = *(const f32x4*)(pfp + 8);
                pf3 = *(const f32x4*)(pfp + 12);
            };
            load_w(cur_e);

            #pragma unroll
            for (int g = 0; g < G; ++g) {
                if (eg[g] != cur_e) { cur_e = eg[g]; load_w(cur_e); }
                f32x4 U = ubv;
                U = __builtin_elementwise_fma(splat4(xr[g][0]), wf0, U);
                U = __builtin_elementwise_fma(splat4(xr[g][1]), wf1, U);
                U = __builtin_elementwise_fma(splat4(xr[g][2]), wf2, U);
                U = __builtin_elementwise_fma(splat4(xr[g][3]), wf3, U);

                // gelu (tanh form, NaN-safe): v - v/(1+t), t = 2^(K*v*(1+b*v^2))
                f32x4 m  = __builtin_elementwise_fma(U * splat4(GELU_B), U, one4);
                f32x4 a  = (U * splat4(GELU_K)) * m;
                f32x4 tt;
                #pragma unroll
                for (int q = 0; q < 4; ++q) tt[q] = __builtin_amdgcn_exp2f(a[q]);
                tt = tt + one4;
                f32x4 r;
                #pragma unroll
                for (int q = 0; q < 4; ++q) r[q] = __builtin_amdgcn_rcpf(tt[q]);
                f32x4 Ug = __builtin_elementwise_fma(-U, r, U);

                acc[g] = __builtin_elementwise_fma(splat4(Ug[0]), pf0, acc[g]);
                acc[g] = __builtin_elementwise_fma(splat4(Ug[1]), pf1, acc[g]);
                acc[g] = __builtin_elementwise_fma(splat4(Ug[2]), pf2, acc[g]);
                acc[g] = __builtin_elementwise_fma(splat4(Ug[3]), pf3, acc[g]);
            }
        }

        // epilogue: combine with gate prob, write back to own slot (bijection)
        #pragma unroll
        for (int g = 0; g < G; ++g) {
            float tp = s_p[sid[g]];
            s_x[sid[g]] = __builtin_elementwise_fma(splat4(tp), acc[g], w_pb);
        }
    }
    __syncthreads();

    // ---------------- Pass 3: coalesced writeback ----------------
    #pragma unroll
    for (int it = 0; it < P1_IT; ++it) {
        const int t_loc = it * TPB + tid;
        o4[gbase + t_loc] = s_x[t_loc];
    }
}

extern "C" void kernel_launch(void* const* d_in, const int* in_sizes, int n_in,
                              void* d_out, int out_size, void* d_ws, size_t ws_size,
                              hipStream_t stream) {
    const float* x  = (const float*)d_in[0];
    const float* ew = (const float*)d_in[1];
    const float* eb = (const float*)d_in[2];
    const float* gw = (const float*)d_in[3];
    const float* wi = (const float*)d_in[4];
    const float* wo = (const float*)d_in[5];
    const float* pw = (const float*)d_in[6];
    const float* pb = (const float*)d_in[7];
    float* ws  = (float*)d_ws;
    float* out = (float*)d_out;

    setup_fused<<<(WS_FLOATS + 255) / 256, 256, 0, stream>>>(ew, eb, gw, wi, wo, pw, pb, ws);
    moe_main<<<NBLK, TPB, 0, stream>>>(x, ws, out);
}

// Round 6
// 62.029 us; speedup vs baseline: 1.6927x; 1.6927x over previous
//
#include <hip/hip_runtime.h>

// Shapes (fixed by the problem)
constexpr int TOK     = 1024 * 2048;  // B*S tokens
constexpr int TPB     = 256;          // threads per block
constexpr int TOK_PB  = 2048;         // tokens per block
constexpr int P1_IT   = TOK_PB / TPB; // 8 pass-1 iters
constexpr int NBLK    = TOK / TOK_PB; // 1024 blocks
constexpr int SID_CAP = 2560;         // 2048 + 8*63 rounded up

typedef float f32x4 __attribute__((ext_vector_type(4)));

// ws float layout (written by setup_fused):
// [0,32)      Gf[k=4][j=8]       = embed_w^T @ gate_w
// [32,40)     gb[8]              = embed_b @ gate_w
// [40,1064)   Wf[e=8][k=4][f=32] = embed_w^T @ wi[e]
// [1064,1320) ub[e=8][f=32]      = embed_b @ wi[e]
// [1320,2344) Pf[e=8][f=32][o=4] = wo[e] @ proj_w^T
// [2344,2348) pb[4]
constexpr int WS_FLOATS = 2348;

__global__ void setup_fused(
    const float* __restrict__ ew,  // [16][4]
    const float* __restrict__ eb,  // [16]
    const float* __restrict__ gw,  // [16][8]
    const float* __restrict__ wi,  // [8][16][32]
    const float* __restrict__ wo,  // [8][32][16]
    const float* __restrict__ pw,  // [4][16]
    const float* __restrict__ pb,  // [4]
    float* __restrict__ ws)
{
    int idx = blockIdx.x * blockDim.x + threadIdx.x;
    if (idx >= WS_FLOATS) return;
    float v = 0.0f;
    if (idx < 32) {
        int k = idx >> 3, j = idx & 7;
        for (int i = 0; i < 16; ++i) v += ew[i * 4 + k] * gw[i * 8 + j];
    } else if (idx < 40) {
        int j = idx - 32;
        for (int i = 0; i < 16; ++i) v += eb[i] * gw[i * 8 + j];
    } else if (idx < 1064) {
        int r = idx - 40; int e = r >> 7, k = (r >> 5) & 3, f = r & 31;
        for (int i = 0; i < 16; ++i) v += ew[i * 4 + k] * wi[(e * 16 + i) * 32 + f];
    } else if (idx < 1320) {
        int r = idx - 1064; int e = r >> 5, f = r & 31;
        for (int i = 0; i < 16; ++i) v += eb[i] * wi[(e * 16 + i) * 32 + f];
    } else if (idx < 2344) {
        int r = idx - 1320; int e = r >> 7, f = (r >> 2) & 31, o = r & 3;
        for (int i = 0; i < 16; ++i) v += wo[(e * 32 + f) * 16 + i] * pw[o * 16 + i];
    } else {
        v = pb[idx - 2344];
    }
    ws[idx] = v;
}

__device__ __forceinline__ f32x4 splat4(float s) { return (f32x4){s, s, s, s}; }

__global__ __launch_bounds__(256) void moe_main(
    const float* __restrict__ x,   // [T][4]
    const float* __restrict__ ws,  // fused weights (global; scalar-loaded)
    float* __restrict__ out)       // [T][4]
{
    __shared__ __align__(16) f32x4          s_x[TOK_PB];    // 32 KB: x -> result
    __shared__ float                        s_p[TOK_PB];    // 8 KB: top_p
    __shared__ __align__(16) unsigned short s_sid[SID_CAP]; // 5 KB: sid|e<<11|pad<<14
    __shared__ int s_cnt[8];
    __shared__ int s_base[8];
    __shared__ int s_padtot;

    const int tid  = threadIdx.x;
    const int lane = tid & 63;
    const unsigned long long lt_mask = (lane == 63) ? 0x7fffffffffffffffull
                                                    : ((1ull << lane) - 1ull);

    if (tid < 8) s_cnt[tid] = 0;

    const int gbase = blockIdx.x * TOK_PB;
    const f32x4* __restrict__ x4 = (const f32x4*)x;
    f32x4* __restrict__ o4       = (f32x4*)out;

    // Wave-uniform gate/proj params (scalar broadcast loads from global).
    f32x4 Gr[8];
    #pragma unroll
    for (int q = 0; q < 8; ++q) Gr[q] = ((const f32x4*)ws)[q];
    const f32x4 w_gb0 = ((const f32x4*)ws)[8];
    const f32x4 w_gb1 = ((const f32x4*)ws)[9];
    const f32x4 w_pb  = ((const f32x4*)(ws + 2344))[0];

    constexpr float LOG2E  = 1.4426950408889634f;
    constexpr float GELU_K = 2.3025850929940457f;   // 2*0.7978845608*log2(e)
    constexpr float GELU_B = 0.044715f;
    const f32x4 one4 = splat4(1.0f);

    __syncthreads();   // s_cnt zeroed

    // ---------------- Pass 1: gate + stash + counting-sort ----------------
    int e_arr[P1_IT], pos_arr[P1_IT];

    #pragma unroll
    for (int it = 0; it < P1_IT; ++it) {
        const int t_loc = it * TPB + tid;
        f32x4 xv = x4[gbase + t_loc];
        s_x[t_loc] = xv;

        f32x4 ga = w_gb0, gb2 = w_gb1;
        #pragma unroll
        for (int k = 0; k < 4; ++k) {
            f32x4 xs = splat4(xv[k]);
            ga  = __builtin_elementwise_fma(xs, Gr[2 * k],     ga);
            gb2 = __builtin_elementwise_fma(xs, Gr[2 * k + 1], gb2);
        }
        float g[8] = {ga[0], ga[1], ga[2], ga[3], gb2[0], gb2[1], gb2[2], gb2[3]};

        float gmax = g[0]; int e = 0;
        #pragma unroll
        for (int j = 1; j < 8; ++j)
            if (g[j] > gmax) { gmax = g[j]; e = j; }
        float ssum = 0.0f;
        #pragma unroll
        for (int j = 0; j < 8; ++j)
            ssum += __builtin_amdgcn_exp2f((g[j] - gmax) * LOG2E);
        s_p[t_loc] = __builtin_amdgcn_rcpf(ssum);

        // wave-aggregated counting: 8 ballots, 8 atomics per wave
        int pos_w = 0, my_cnt = 0;
        #pragma unroll
        for (int j = 0; j < 8; ++j) {
            unsigned long long bj = __ballot(e == j);
            int pc_lt = __popcll(bj & lt_mask);
            int pc    = __popcll(bj);
            if (e == j)    pos_w  = pc_lt;
            if (lane == j) my_cnt = pc;
        }
        int base_w = 0;
        if (lane < 8) base_w = atomicAdd(&s_cnt[lane], my_cnt);
        int base = __shfl(base_w, e, 64);
        e_arr[it]   = e;
        pos_arr[it] = base + pos_w;
    }
    __syncthreads();

    // 64-aligned padded bases: every expert run starts at a multiple of 64
    // and is padded to a multiple of 64 -> every wave in pass 2 is
    // expert-uniform BY CONSTRUCTION.
    if (tid == 0) {
        int run = 0;
        #pragma unroll
        for (int j = 0; j < 8; ++j) {
            s_base[j] = run;
            run += (s_cnt[j] + 63) & ~63;
        }
        s_padtot = run;
    }
    __syncthreads();

    const int padtot = s_padtot;

    // Fill all padded slots with discard markers carrying the run's expert.
    #pragma unroll 1
    for (int s = tid; s < padtot; s += TPB) {
        int e = 0;
        #pragma unroll
        for (int j = 1; j < 8; ++j)
            if (s >= s_base[j]) e = j;      // largest j with base<=s
        s_sid[s] = (unsigned short)((e << 11) | (1u << 14));
    }
    __syncthreads();

    // Scatter real tokens over the markers.
    #pragma unroll
    for (int it = 0; it < P1_IT; ++it) {
        const int t_loc = it * TPB + tid;
        const int slot  = s_base[e_arr[it]] + pos_arr[it];
        s_sid[slot] = (unsigned short)(t_loc | (e_arr[it] << 11));
    }
    __syncthreads();

    // ---- Pass 2: expert-uniform waves; weights via SCALAR loads (SGPR) ----
    #pragma unroll 1
    for (int s = tid; s < padtot; s += TPB) {
        const unsigned v = s_sid[s];
        const int sid   = (int)(v & 2047u);
        const bool live = (v & (1u << 14)) == 0;
        // wave-uniform expert id -> scalar weight addressing
        const int eu = __builtin_amdgcn_readfirstlane((int)((v >> 11) & 7u));

        f32x4 xv = s_x[sid];

        const float* __restrict__ wf = ws + 40   + eu * 128;  // [k=4][f=32]
        const float* __restrict__ ub = ws + 1064 + eu * 32;   // [f=32]
        const float* __restrict__ pf = ws + 1320 + eu * 128;  // [f=32][o=4]

        f32x4 acc = splat4(0.0f);

        #pragma unroll 1
        for (int c = 0; c < 4; ++c) {        // 4 chunks of 8 hidden elems
            // U chunk = ub + x @ Wf (weights -> SGPRs, ~72 live)
            f32x4 Ua = *(const f32x4*)(ub + c * 8);
            f32x4 Ub = *(const f32x4*)(ub + c * 8 + 4);
            #pragma unroll
            for (int k = 0; k < 4; ++k) {
                const float* w = wf + k * 32 + c * 8;
                f32x4 xs = splat4(xv[k]);
                Ua = __builtin_elementwise_fma(xs, *(const f32x4*)(w),     Ua);
                Ub = __builtin_elementwise_fma(xs, *(const f32x4*)(w + 4), Ub);
            }

            // gelu (tanh form, NaN-safe): v - v/(1+t), t = 2^(K*v*(1+b*v^2))
            {
                f32x4 m  = __builtin_elementwise_fma(Ua * splat4(GELU_B), Ua, one4);
                f32x4 a  = (Ua * splat4(GELU_K)) * m;
                f32x4 tt;
                #pragma unroll
                for (int q = 0; q < 4; ++q) tt[q] = __builtin_amdgcn_exp2f(a[q]);
                tt = tt + one4;
                f32x4 r;
                #pragma unroll
                for (int q = 0; q < 4; ++q) r[q] = __builtin_amdgcn_rcpf(tt[q]);
                Ua = __builtin_elementwise_fma(-Ua, r, Ua);
            }
            {
                f32x4 m  = __builtin_elementwise_fma(Ub * splat4(GELU_B), Ub, one4);
                f32x4 a  = (Ub * splat4(GELU_K)) * m;
                f32x4 tt;
                #pragma unroll
                for (int q = 0; q < 4; ++q) tt[q] = __builtin_amdgcn_exp2f(a[q]);
                tt = tt + one4;
                f32x4 r;
                #pragma unroll
                for (int q = 0; q < 4; ++q) r[q] = __builtin_amdgcn_rcpf(tt[q]);
                Ub = __builtin_elementwise_fma(-Ub, r, Ub);
            }

            // acc += gelu(U) @ Pf chunk
            const float* pfc = pf + c * 32;
            #pragma unroll
            for (int f = 0; f < 4; ++f) {
                acc = __builtin_elementwise_fma(splat4(Ua[f]),
                        *(const f32x4*)(pfc + f * 4), acc);
                acc = __builtin_elementwise_fma(splat4(Ub[f]),
                        *(const f32x4*)(pfc + 16 + f * 4), acc);
            }
        }

        if (live) {
            float tp = s_p[sid];
            s_x[sid] = __builtin_elementwise_fma(splat4(tp), acc, w_pb);
        }
    }
    __syncthreads();

    // ---------------- Pass 3: coalesced writeback ----------------
    #pragma unroll
    for (int it = 0; it < P1_IT; ++it) {
        const int t_loc = it * TPB + tid;
        o4[gbase + t_loc] = s_x[t_loc];
    }
}

extern "C" void kernel_launch(void* const* d_in, const int* in_sizes, int n_in,
                              void* d_out, int out_size, void* d_ws, size_t ws_size,
                              hipStream_t stream) {
    const float* x  = (const float*)d_in[0];
    const float* ew = (const float*)d_in[1];
    const float* eb = (const float*)d_in[2];
    const float* gw = (const float*)d_in[3];
    const float* wi = (const float*)d_in[4];
    const float* wo = (const float*)d_in[5];
    const float* pw = (const float*)d_in[6];
    const float* pb = (const float*)d_in[7];
    float* ws  = (float*)d_ws;
    float* out = (float*)d_out;

    setup_fused<<<(WS_FLOATS + 255) / 256, 256, 0, stream>>>(ew, eb, gw, wi, wo, pw, pb, ws);
    moe_main<<<NBLK, TPB, 0, stream>>>(x, ws, out);
}

// Round 8
// 46.747 us; speedup vs baseline: 2.2461x; 1.3269x over previous
//
#include <hip/hip_runtime.h>

// Shapes (fixed by the problem)
constexpr int TOK   = 1024 * 2048;           // B*S tokens
constexpr int TPB   = 256;
constexpr int NBLK  = 2048;
constexpr int ITERS = TOK / (NBLK * TPB);    // 4 tokens per thread

typedef float  f32x4 __attribute__((ext_vector_type(4)));
typedef __fp16 h2    __attribute__((ext_vector_type(2)));

// ws word layout (u32 words; f32 bit-pattern for the fp32 region):
// [0,32)     Gf[k=4][j=8]  f32   = embed_w^T @ gate_w
// [32,40)    gb[8]         f32   = embed_b @ gate_w
// [40,44)    pb[4]         f32
// [44,556)   hWf[e][f=32][p=2]   f16x2 {Wf[2p][f],Wf[2p+1][f]}
// [556,684)  hUb[e][j=16]        f16x2 {ub[2j],ub[2j+1]}
// [684,1196) hPf[e][j=16][o=4]   f16x2 {Pf[2j][o],Pf[2j+1][o]}
constexpr int OFF_GF = 0, OFF_GB = 32, OFF_PB = 40;
constexpr int OFF_WF = 44, OFF_UB = 556, OFF_PF = 684, WS_W = 1196;
// LDS expert strides padded (stride % 32 == 4 words) like R0/R1 (0 conflicts).
constexpr int WF_S = 68, UB_S = 20, PF_S = 68;

__device__ __forceinline__ unsigned pk16(float a, float b) {
    unsigned ua = (unsigned)__builtin_bit_cast(unsigned short, (__fp16)a);
    unsigned ub = (unsigned)__builtin_bit_cast(unsigned short, (__fp16)b);
    return ua | (ub << 16);
}

__global__ void setup_fused(
    const float* __restrict__ ew,  // [16][4]
    const float* __restrict__ eb,  // [16]
    const float* __restrict__ gw,  // [16][8]
    const float* __restrict__ wi,  // [8][16][32]
    const float* __restrict__ wo,  // [8][32][16]
    const float* __restrict__ pw,  // [4][16]
    const float* __restrict__ pb,  // [4]
    unsigned* __restrict__ wsu)
{
    int idx = blockIdx.x * blockDim.x + threadIdx.x;
    if (idx >= WS_W) return;
    float* wsf = (float*)wsu;
    if (idx < OFF_GB) {
        int k = idx >> 3, j = idx & 7;
        float v = 0.f;
        for (int i = 0; i < 16; ++i) v += ew[i * 4 + k] * gw[i * 8 + j];
        wsf[idx] = v;
    } else if (idx < OFF_PB) {
        int j = idx - OFF_GB;
        float v = 0.f;
        for (int i = 0; i < 16; ++i) v += eb[i] * gw[i * 8 + j];
        wsf[idx] = v;
    } else if (idx < OFF_WF) {
        wsf[idx] = pb[idx - OFF_PB];
    } else if (idx < OFF_UB) {
        int r = idx - OFF_WF; int e = r >> 6, t = r & 63, f = t >> 1, p = t & 1;
        float v0 = 0.f, v1 = 0.f;
        for (int i = 0; i < 16; ++i) {
            float w = wi[(e * 16 + i) * 32 + f];
            v0 += ew[i * 4 + 2 * p]     * w;
            v1 += ew[i * 4 + 2 * p + 1] * w;
        }
        wsu[idx] = pk16(v0, v1);
    } else if (idx < OFF_PF) {
        int r = idx - OFF_UB; int e = r >> 4, j = r & 15;
        float v0 = 0.f, v1 = 0.f;
        for (int i = 0; i < 16; ++i) {
            v0 += eb[i] * wi[(e * 16 + i) * 32 + 2 * j];
            v1 += eb[i] * wi[(e * 16 + i) * 32 + 2 * j + 1];
        }
        wsu[idx] = pk16(v0, v1);
    } else {
        int r = idx - OFF_PF; int e = r >> 6, t = r & 63, j = t >> 2, o = t & 3;
        float v0 = 0.f, v1 = 0.f;
        for (int i = 0; i < 16; ++i) {
            float p = pw[o * 16 + i];
            v0 += wo[(e * 32 + 2 * j)     * 16 + i] * p;
            v1 += wo[(e * 32 + 2 * j + 1) * 16 + i] * p;
        }
        wsu[idx] = pk16(v0, v1);
    }
}

__device__ __forceinline__ f32x4 splat4(float s) { return (f32x4){s, s, s, s}; }
__device__ __forceinline__ h2 bch2(unsigned u) { return __builtin_bit_cast(h2, u); }

__global__ __launch_bounds__(256) void moe_main(
    const float* __restrict__ x,      // [T][4]
    const unsigned* __restrict__ wsu, // fused weights
    float* __restrict__ out)          // [T][4]
{
    __shared__ __align__(16) unsigned sWf[8 * WF_S];
    __shared__ __align__(16) unsigned sUb[8 * UB_S];
    __shared__ __align__(16) unsigned sPf[8 * PF_S];

    const float* wsf = (const float*)wsu;
    const int tid = threadIdx.x;

    for (int i = tid; i < 512; i += TPB) {
        int e = i >> 6, r = i & 63;
        sWf[e * WF_S + r] = wsu[OFF_WF + i];
        sPf[e * PF_S + r] = wsu[OFF_PF + i];
    }
    if (tid < 128) {
        int e = tid >> 4, r = tid & 15;
        sUb[e * UB_S + r] = wsu[OFF_UB + tid];
    }

    const f32x4* __restrict__ x4 = (const f32x4*)x;
    f32x4* __restrict__ o4       = (f32x4*)out;

    // Wave-uniform gate/proj params (broadcast f32 loads from global).
    f32x4 Gr[8];
    #pragma unroll
    for (int q = 0; q < 8; ++q) Gr[q] = ((const f32x4*)wsf)[q];
    const f32x4 w_gb0 = ((const f32x4*)wsf)[8];
    const f32x4 w_gb1 = ((const f32x4*)wsf)[9];
    const f32x4 w_pb  = *(const f32x4*)(wsf + OFF_PB);

    constexpr float LOG2E  = 1.4426950408889634f;
    constexpr float GELU_K = 2.3025850929940457f;   // 2*0.7978845608*log2(e)
    constexpr float GELU_B = 0.044715f;
    const f32x4 one4 = splat4(1.0f);

    __syncthreads();

    int t = blockIdx.x * TPB + tid;
    for (int it = 0; it < ITERS; ++it, t += NBLK * TPB) {
        f32x4 xv = x4[t];

        // --- gate logits (f32, identical to R1 -> routing unchanged) ---
        f32x4 ga = w_gb0, gb2 = w_gb1;
        #pragma unroll
        for (int k = 0; k < 4; ++k) {
            f32x4 xs = splat4(xv[k]);
            ga  = __builtin_elementwise_fma(xs, Gr[2 * k],     ga);
            gb2 = __builtin_elementwise_fma(xs, Gr[2 * k + 1], gb2);
        }
        float g[8] = {ga[0], ga[1], ga[2], ga[3], gb2[0], gb2[1], gb2[2], gb2[3]};

        float gmax = g[0]; int e = 0;
        #pragma unroll
        for (int j = 1; j < 8; ++j)
            if (g[j] > gmax) { gmax = g[j]; e = j; }
        float ssum = 0.0f;
        #pragma unroll
        for (int j = 0; j < 8; ++j)
            ssum += __builtin_amdgcn_exp2f((g[j] - gmax) * LOG2E);
        float tp = __builtin_amdgcn_rcpf(ssum);

        // --- expert FFN in f16 (dot2, f32 accumulate) ---
        h2 x01 = __builtin_amdgcn_cvt_pkrtz(xv[0], xv[1]);
        h2 x23 = __builtin_amdgcn_cvt_pkrtz(xv[2], xv[3]);

        const uint4* __restrict__ wf4 = (const uint4*)(sWf + e * WF_S);
        const uint4* __restrict__ ub4 = (const uint4*)(sUb + e * UB_S);
        const uint4* __restrict__ pf4 = (const uint4*)(sPf + e * PF_S);

        uint4 ubv0 = ub4[0], ubv1 = ub4[1], ubv2 = ub4[2], ubv3 = ub4[3];
        unsigned ubw[16] = {ubv0.x, ubv0.y, ubv0.z, ubv0.w,
                            ubv1.x, ubv1.y, ubv1.z, ubv1.w,
                            ubv2.x, ubv2.y, ubv2.z, ubv2.w,
                            ubv3.x, ubv3.y, ubv3.z, ubv3.w};

        f32x4 Ug[8];
        #pragma unroll
        for (int j = 0; j < 8; ++j) {           // f = 4j .. 4j+3
            uint4 wa = wf4[2 * j];              // f=4j, 4j+1
            uint4 wb = wf4[2 * j + 1];          // f=4j+2, 4j+3
            h2 hb0 = bch2(ubw[2 * j]);          // ub[4j], ub[4j+1]
            h2 hb1 = bch2(ubw[2 * j + 1]);      // ub[4j+2], ub[4j+3]
            f32x4 U;
            U[0] = __builtin_amdgcn_fdot2(x01, bch2(wa.x),
                     __builtin_amdgcn_fdot2(x23, bch2(wa.y), (float)hb0.x, false), false);
            U[1] = __builtin_amdgcn_fdot2(x01, bch2(wa.z),
                     __builtin_amdgcn_fdot2(x23, bch2(wa.w), (float)hb0.y, false), false);
            U[2] = __builtin_amdgcn_fdot2(x01, bch2(wb.x),
                     __builtin_amdgcn_fdot2(x23, bch2(wb.y), (float)hb1.x, false), false);
            U[3] = __builtin_amdgcn_fdot2(x01, bch2(wb.z),
                     __builtin_amdgcn_fdot2(x23, bch2(wb.w), (float)hb1.y, false), false);
            Ug[j] = U;
        }

        // --- gelu (tanh form, NaN-safe): v - v/(1+t), t = 2^(K*v*(1+b*v^2)) ---
        #pragma unroll
        for (int j = 0; j < 8; ++j) {
            f32x4 vv = Ug[j];
            f32x4 m  = __builtin_elementwise_fma(vv * splat4(GELU_B), vv, one4);
            f32x4 a  = (vv * splat4(GELU_K)) * m;
            f32x4 tt;
            #pragma unroll
            for (int q = 0; q < 4; ++q) tt[q] = __builtin_amdgcn_exp2f(a[q]);
            tt = tt + one4;
            f32x4 r;
            #pragma unroll
            for (int q = 0; q < 4; ++q) r[q] = __builtin_amdgcn_rcpf(tt[q]);
            Ug[j] = __builtin_elementwise_fma(-vv, r, vv);
        }

        // --- PV: acc_o = sum_f gelu(U)_f * Pf[f][o]  (f16 pairs, f32 acc) ---
        f32x4 acc = splat4(0.0f);
        #pragma unroll
        for (int j = 0; j < 8; ++j) {
            h2 a01 = __builtin_amdgcn_cvt_pkrtz(Ug[j][0], Ug[j][1]);  // pair 2j
            h2 a23 = __builtin_amdgcn_cvt_pkrtz(Ug[j][2], Ug[j][3]);  // pair 2j+1
            uint4 p0 = pf4[2 * j];
            uint4 p1 = pf4[2 * j + 1];
            acc[0] = __builtin_amdgcn_fdot2(a01, bch2(p0.x), acc[0], false);
            acc[1] = __builtin_amdgcn_fdot2(a01, bch2(p0.y), acc[1], false);
            acc[2] = __builtin_amdgcn_fdot2(a01, bch2(p0.z), acc[2], false);
            acc[3] = __builtin_amdgcn_fdot2(a01, bch2(p0.w), acc[3], false);
            acc[0] = __builtin_amdgcn_fdot2(a23, bch2(p1.x), acc[0], false);
            acc[1] = __builtin_amdgcn_fdot2(a23, bch2(p1.y), acc[1], false);
            acc[2] = __builtin_amdgcn_fdot2(a23, bch2(p1.z), acc[2], false);
            acc[3] = __builtin_amdgcn_fdot2(a23, bch2(p1.w), acc[3], false);
        }

        o4[t] = __builtin_elementwise_fma(splat4(tp), acc, w_pb);
    }
}

extern "C" void kernel_launch(void* const* d_in, const int* in_sizes, int n_in,
                              void* d_out, int out_size, void* d_ws, size_t ws_size,
                              hipStream_t stream) {
    const float* x  = (const float*)d_in[0];
    const float* ew = (const float*)d_in[1];
    const float* eb = (const float*)d_in[2];
    const float* gw = (const float*)d_in[3];
    const float* wi = (const float*)d_in[4];
    const float* wo = (const float*)d_in[5];
    const float* pw = (const float*)d_in[6];
    const float* pb = (const float*)d_in[7];
    unsigned* wsu = (unsigned*)d_ws;
    float* out    = (float*)d_out;

    setup_fused<<<(WS_W + 255) / 256, 256, 0, stream>>>(ew, eb, gw, wi, wo, pw, pb, wsu);
    moe_main<<<NBLK, TPB, 0, stream>>>(x, wsu, out);
}